// Round 2
// baseline (1960.540 us; speedup 1.0000x reference)
//
#include <hip/hip_runtime.h>
#include <cmath>

// Problem constants (fixed by reference): B=8, N=2048, eps=0.01, 50 iters.
#define BATCH 8
#define NPT   2048
#define NPTS  (BATCH * NPT)
#define TILES 32                      // blocks per batch (64 rows each)
#define GRID_MAIN (BATCH * TILES)     // 256 blocks = 1 per CU avg; 2 fit/CU -> all resident
#define THREADS 256
#define RPW   16                      // rows per wave
#define ITERS 50

// exp(v_j - 100*cost) = exp2( C_LOG2E*v_j + NEG100C*(n_i + n_j) + S200C*dot )
#define C_LOG2E 1.4426950408889634f
#define NEG100C (-144.26950408889634f)   // -100 * log2(e)
#define S200C   288.53900817779268f      //  200 * log2(e)
#define EPS_LOG 1e-8f
#define LN2_01  0.006931471805599453f    // 0.01 * ln(2)

static __device__ __forceinline__ float fast_exp2(float x) {
#if __has_builtin(__builtin_amdgcn_exp2f)
    return __builtin_amdgcn_exp2f(x);   // raw v_exp_f32
#else
    return exp2f(x);
#endif
}

// Coherent (agent-scope, sc1) accessors for the cross-block dual arrays.
// These complete at the chip coherence point -> immune to per-XCD L2 staleness.
static __device__ __forceinline__ float gload(const float* p) {
    return __hip_atomic_load(p, __ATOMIC_RELAXED, __HIP_MEMORY_SCOPE_AGENT);
}
static __device__ __forceinline__ void gstore(float* p, float val) {
    __hip_atomic_store(p, val, __ATOMIC_RELAXED, __HIP_MEMORY_SCOPE_AGENT);
}

// ---------------------------------------------------------------------------
// Tiny init: zero EMD outputs and per-batch barrier counters.
// ---------------------------------------------------------------------------
__global__ void init_kernel(float* __restrict__ out,
                            unsigned int* __restrict__ ctr) {
    int t = threadIdx.x;
    if (t < BATCH) out[t] = 0.0f;
    ctr[t] = 0u;   // BATCH*32 = 256 slots, 128B padding per batch
}

// ---------------------------------------------------------------------------
// Per-batch monotonic barrier: TILES blocks arrive (release), rep spins with
// acquire loads. Counter never resets; target = TILES * phase.
// __syncthreads() drains each wave's vmcnt before arrival, so all block
// stores (sc1, coherence-point) are globally visible before the RMW.
// ---------------------------------------------------------------------------
static __device__ __forceinline__ void batch_barrier(unsigned int* bar,
                                                     unsigned int target) {
    __syncthreads();
    if (threadIdx.x == 0) {
        __hip_atomic_fetch_add(bar, 1u, __ATOMIC_RELEASE,
                               __HIP_MEMORY_SCOPE_AGENT);
        while (__hip_atomic_load(bar, __ATOMIC_ACQUIRE,
                                 __HIP_MEMORY_SCOPE_AGENT) < target) {
            __builtin_amdgcn_s_sleep(2);
        }
    }
    __syncthreads();
}

// ---------------------------------------------------------------------------
// One Sinkhorn half-step over a persistent LDS column tile:
//   dual_out_i = log_mu - log( sum_j exp2( dot_scl + rc_i + w_j ) + 1e-8 )
// ---------------------------------------------------------------------------
static __device__ __forceinline__ void half_pass(
        const float4* cd,
        const float (&rx)[RPW], const float (&ry)[RPW],
        const float (&rz)[RPW], const float (&rc)[RPW],
        float* __restrict__ dual_out, int outbase, int lane, float log_mu)
{
    float acc[RPW];
#pragma unroll
    for (int r = 0; r < RPW; r++) acc[r] = 0.0f;

    for (int jc = 0; jc < NPT; jc += 64) {
        float4 y = cd[jc + lane];
#pragma unroll
        for (int r = 0; r < RPW; r++) {
            float t = fmaf(rx[r], y.x, rc[r]);
            t = fmaf(ry[r], y.y, t);
            t = fmaf(rz[r], y.z, t);
            t += y.w;
            acc[r] += fast_exp2(t);
        }
    }

#pragma unroll
    for (int r = 0; r < RPW; r++) {
        float s = acc[r];
#pragma unroll
        for (int m = 32; m >= 1; m >>= 1) s += __shfl_xor(s, m, 64);
        if (lane == r) gstore(&dual_out[outbase + r], log_mu - logf(s + EPS_LOG));
    }
}

// ---------------------------------------------------------------------------
// Fused persistent kernel (regular launch): stage both column tiles once,
// run all 50 iterations with per-batch barriers, fused EMD epilogue.
// LDS = 2 * 32 KB = 64 KB; 256 blocks over 256 CUs (2 fit/CU -> residency).
// ---------------------------------------------------------------------------
__global__ __launch_bounds__(THREADS) void sinkhorn_kernel(
        const float* __restrict__ x1, const float* __restrict__ x2,
        float* __restrict__ u, float* __restrict__ v,
        unsigned int* __restrict__ ctr, float* __restrict__ out)
{
    __shared__ float4 cd1[NPT];   // side-1 columns (dual = u)
    __shared__ float4 cd2[NPT];   // side-2 columns (dual = v)

    const int b    = blockIdx.x / TILES;
    const int tile = blockIdx.x % TILES;
    const int base = b * NPT;
    unsigned int* bar = ctr + b * 32;   // 128B-padded per-batch counter

    const int tid  = threadIdx.x;
    const int wave = tid >> 6;
    const int lane = tid & 63;
    const int row0 = tile * 64 + wave * RPW;

    const float log_mu = logf(1.0f / (float)NPT + EPS_LOG);   // == log_nu

    // ---- one-time column staging (scaled, w = P = -100*log2e*|p|^2) ----
    float P1[8], P2[8];
#pragma unroll
    for (int k = 0; k < 8; k++) {
        int j = tid + THREADS * k;
        const float* p = x1 + 3 * (base + j);
        float a = p[0], bb = p[1], c = p[2];
        float n = fmaf(a, a, fmaf(bb, bb, c * c));
        P1[k] = n * NEG100C;
        cd1[j] = make_float4(a * S200C, bb * S200C, c * S200C, P1[k]);
        p = x2 + 3 * (base + j);
        a = p[0]; bb = p[1]; c = p[2];
        n = fmaf(a, a, fmaf(bb, bb, c * c));
        P2[k] = n * NEG100C;
        cd2[j] = make_float4(a * S200C, bb * S200C, c * S200C, P2[k]);
    }

    // ---- one-time row registers (wave-uniform) for both sides ----
    float rx1[RPW], ry1[RPW], rz1[RPW], rc1[RPW];
    float rx2[RPW], ry2[RPW], rz2[RPW], rc2[RPW];
#pragma unroll
    for (int r = 0; r < RPW; r++) {
        const float* p = x1 + 3 * (base + row0 + r);
        rx1[r] = p[0]; ry1[r] = p[1]; rz1[r] = p[2];
        rc1[r] = NEG100C * fmaf(rx1[r], rx1[r],
                                fmaf(ry1[r], ry1[r], rz1[r] * rz1[r]));
        p = x2 + 3 * (base + row0 + r);
        rx2[r] = p[0]; ry2[r] = p[1]; rz2[r] = p[2];
        rc2[r] = NEG100C * fmaf(rx2[r], rx2[r],
                                fmaf(ry2[r], ry2[r], rz2[r] * rz2[r]));
    }
    __syncthreads();

    // ---- 50 Sinkhorn iterations, 2 per-batch barriers each ----
    unsigned int phase = 0;
    for (int it = 0; it < ITERS; it++) {
        if (it > 0) {   // fold fresh v into cd2.w (iter 0: v=0 -> w=P already)
#pragma unroll
            for (int k = 0; k < 8; k++) {
                int j = tid + THREADS * k;
                cd2[j].w = fmaf(C_LOG2E, gload(&v[base + j]), P2[k]);
            }
            __syncthreads();
        }
        // u_i = log_mu - log(sum_j K_ij e^{v_j} + eps)
        half_pass(cd2, rx1, ry1, rz1, rc1, u, base + row0, lane, log_mu);
        batch_barrier(bar, (unsigned)TILES * (++phase));   // publish u

#pragma unroll
        for (int k = 0; k < 8; k++) {          // fold fresh u into cd1.w
            int j = tid + THREADS * k;
            cd1[j].w = fmaf(C_LOG2E, gload(&u[base + j]), P1[k]);
        }
        __syncthreads();
        // v_j = log_nu - log(sum_i K_ij e^{u_i} + eps)
        half_pass(cd1, rx2, ry2, rz2, rc2, v, base + row0, lane, log_mu);
        batch_barrier(bar, (unsigned)TILES * (++phase));   // publish v
    }

    // ---- fused EMD epilogue: emd[b] = sum_ij exp2(t) * cost,
    //      cost = 0.01*(u_i+v_j) - 0.01*ln2 * t  (algebraically exact) ----
    float* cv = reinterpret_cast<float*>(cd1);   // cd1 space reused
#pragma unroll
    for (int k = 0; k < 8; k++) {
        int j = tid + THREADS * k;
        float vj = gload(&v[base + j]);
        cd2[j].w = fmaf(C_LOG2E, vj, P2[k]);
        cv[j] = 0.01f * vj;
    }
    __syncthreads();

    float rcc[RPW], su[RPW];
#pragma unroll
    for (int r = 0; r < RPW; r++) {
        float ur = gload(&u[base + row0 + r]);   // written by this block
        rcc[r] = fmaf(C_LOG2E, ur, rc1[r]);
        su[r]  = 0.01f * ur;
    }

    float eacc = 0.0f;
    for (int jc = 0; jc < NPT; jc += 64) {
        float4 y  = cd2[jc + lane];
        float cvl = cv[jc + lane];
#pragma unroll
        for (int r = 0; r < RPW; r++) {
            float t = fmaf(rx1[r], y.x, rcc[r]);
            t = fmaf(ry1[r], y.y, t);
            t = fmaf(rz1[r], y.z, t);
            t += y.w;
            float cost = fmaf(-LN2_01, t, su[r] + cvl);
            eacc = fmaf(fast_exp2(t), cost, eacc);
        }
    }
#pragma unroll
    for (int m = 32; m >= 1; m >>= 1) eacc += __shfl_xor(eacc, m, 64);

    __syncthreads();   // all waves done reading cv before reusing cd1 space
    float* wsum = reinterpret_cast<float*>(cd1);
    if (lane == 0) wsum[wave] = eacc;
    __syncthreads();
    if (tid == 0) atomicAdd(&out[b], wsum[0] + wsum[1] + wsum[2] + wsum[3]);
}

// ---------------------------------------------------------------------------
extern "C" void kernel_launch(void* const* d_in, const int* in_sizes, int n_in,
                              void* d_out, int out_size, void* d_ws, size_t ws_size,
                              hipStream_t stream) {
    (void)in_sizes; (void)n_in; (void)out_size; (void)ws_size;
    const float* x1 = (const float*)d_in[0];
    const float* x2 = (const float*)d_in[1];
    float* out = (float*)d_out;

    char* ws = (char*)d_ws;
    float* u = (float*)ws;                           // NPTS floats
    float* v = u + NPTS;                             // NPTS floats
    unsigned int* ctr = (unsigned int*)(v + NPTS);   // BATCH*32 uints

    init_kernel<<<1, 256, 0, stream>>>(out, ctr);
    sinkhorn_kernel<<<GRID_MAIN, THREADS, 0, stream>>>(x1, x2, u, v, ctr, out);
}

// Round 3
// 1738.717 us; speedup vs baseline: 1.1276x; 1.1276x over previous
//
#include <hip/hip_runtime.h>
#include <cmath>

// Problem constants (fixed by reference): B=8, N=2048, eps=0.01, 50 iters.
#define BATCH 8
#define NPT   2048
#define NPTS  (BATCH * NPT)
#define TILES 64                      // blocks per batch (32 rows each)
#define GRID_MAIN (BATCH * TILES)     // 512 blocks = 2/CU (64KB LDS each -> both resident)
#define THREADS 256
#define RPW   8                       // rows per wave
#define ITERS 50

// exp(v_j - 100*cost) = exp2( C_LOG2E*v_j + NEG100C*(n_i + n_j) + S200C*dot )
#define C_LOG2E 1.4426950408889634f
#define NEG100C (-144.26950408889634f)   // -100 * log2(e)
#define S200C   288.53900817779268f      //  200 * log2(e)
#define EPS_LOG 1e-8f
#define LN2_01  0.006931471805599453f    // 0.01 * ln(2)

static __device__ __forceinline__ float fast_exp2(float x) {
#if __has_builtin(__builtin_amdgcn_exp2f)
    return __builtin_amdgcn_exp2f(x);   // raw v_exp_f32
#else
    return exp2f(x);
#endif
}

// Coherent (agent-scope) accessors for the cross-block dual arrays.
// Complete at the chip coherence point -> immune to per-XCD L2 staleness.
static __device__ __forceinline__ float gload(const float* p) {
    return __hip_atomic_load(p, __ATOMIC_RELAXED, __HIP_MEMORY_SCOPE_AGENT);
}
static __device__ __forceinline__ void gstore(float* p, float val) {
    __hip_atomic_store(p, val, __ATOMIC_RELAXED, __HIP_MEMORY_SCOPE_AGENT);
}

// ---------------------------------------------------------------------------
// Tiny init: zero EMD outputs and per-batch barrier counters.
// ---------------------------------------------------------------------------
__global__ void init_kernel(float* __restrict__ out,
                            unsigned int* __restrict__ ctr) {
    int t = threadIdx.x;
    if (t < BATCH) out[t] = 0.0f;
    ctr[t] = 0u;   // BATCH*32 = 256 slots, 128B padding per batch
}

// ---------------------------------------------------------------------------
// Per-batch monotonic barrier: TILES blocks arrive (release), rep spins with
// acquire loads. Counter never resets; target = TILES * phase.
// ---------------------------------------------------------------------------
static __device__ __forceinline__ void batch_barrier(unsigned int* bar,
                                                     unsigned int target) {
    __syncthreads();
    if (threadIdx.x == 0) {
        __hip_atomic_fetch_add(bar, 1u, __ATOMIC_RELEASE,
                               __HIP_MEMORY_SCOPE_AGENT);
        while (__hip_atomic_load(bar, __ATOMIC_ACQUIRE,
                                 __HIP_MEMORY_SCOPE_AGENT) < target) {
            __builtin_amdgcn_s_sleep(2);
        }
    }
    __syncthreads();
}

// ---------------------------------------------------------------------------
// One Sinkhorn half-step over a persistent LDS column tile:
//   dual_out_i = log_mu - log( sum_j exp2( dot_scl + rc_i + w_j ) + 1e-8 )
// ---------------------------------------------------------------------------
static __device__ __forceinline__ void half_pass(
        const float4* cd,
        const float (&rx)[RPW], const float (&ry)[RPW],
        const float (&rz)[RPW], const float (&rc)[RPW],
        float* __restrict__ dual_out, int outbase, int lane, float log_mu)
{
    float acc[RPW];
#pragma unroll
    for (int r = 0; r < RPW; r++) acc[r] = 0.0f;

    for (int jc = 0; jc < NPT; jc += 128) {
        float4 y0 = cd[jc + lane];          // both ds_read_b128 issue together;
        float4 y1 = cd[jc + 64 + lane];     // y1 latency hides under y0 compute
#pragma unroll
        for (int r = 0; r < RPW; r++) {
            float t0 = fmaf(rx[r], y0.x, rc[r]);
            t0 = fmaf(ry[r], y0.y, t0);
            t0 = fmaf(rz[r], y0.z, t0);
            t0 += y0.w;
            acc[r] += fast_exp2(t0);
            float t1 = fmaf(rx[r], y1.x, rc[r]);
            t1 = fmaf(ry[r], y1.y, t1);
            t1 = fmaf(rz[r], y1.z, t1);
            t1 += y1.w;
            acc[r] += fast_exp2(t1);
        }
    }

    // Butterfly-reduce each row; select row r's total into lane r, then one
    // wave-uniform fast log (no divergent logf expansions).
    float sel = 1.0f;
#pragma unroll
    for (int r = 0; r < RPW; r++) {
        float s = acc[r];
#pragma unroll
        for (int m = 32; m >= 1; m >>= 1) s += __shfl_xor(s, m, 64);
        if (lane == r) sel = s;
    }
    float res = log_mu - __logf(sel + EPS_LOG);
    if (lane < RPW) gstore(&dual_out[outbase + lane], res);
}

// ---------------------------------------------------------------------------
// Fused persistent kernel (regular launch): stage both column tiles once,
// run all 50 iterations with per-batch barriers, fused EMD epilogue.
// LDS = 64 KB; 512 blocks -> 2/CU (co-resident blocks are from different
// batches, so barrier spin of one overlaps compute of the other).
// ---------------------------------------------------------------------------
__global__ __launch_bounds__(THREADS) void sinkhorn_kernel(
        const float* __restrict__ x1, const float* __restrict__ x2,
        float* __restrict__ u, float* __restrict__ v,
        unsigned int* __restrict__ ctr, float* __restrict__ out)
{
    __shared__ float4 cd1[NPT];   // side-1 columns (dual = u)
    __shared__ float4 cd2[NPT];   // side-2 columns (dual = v)

    const int b    = blockIdx.x / TILES;
    const int tile = blockIdx.x % TILES;
    const int base = b * NPT;
    unsigned int* bar = ctr + b * 32;   // 128B-padded per-batch counter

    const int tid  = threadIdx.x;
    const int wave = tid >> 6;
    const int lane = tid & 63;
    const int row0 = tile * 32 + wave * RPW;

    const float log_mu = logf(1.0f / (float)NPT + EPS_LOG);   // == log_nu

    // ---- one-time column staging (scaled, w = P = -100*log2e*|p|^2) ----
    float P1[8], P2[8];
#pragma unroll
    for (int k = 0; k < 8; k++) {
        int j = tid + THREADS * k;
        const float* p = x1 + 3 * (base + j);
        float a = p[0], bb = p[1], c = p[2];
        float n = fmaf(a, a, fmaf(bb, bb, c * c));
        P1[k] = n * NEG100C;
        cd1[j] = make_float4(a * S200C, bb * S200C, c * S200C, P1[k]);
        p = x2 + 3 * (base + j);
        a = p[0]; bb = p[1]; c = p[2];
        n = fmaf(a, a, fmaf(bb, bb, c * c));
        P2[k] = n * NEG100C;
        cd2[j] = make_float4(a * S200C, bb * S200C, c * S200C, P2[k]);
    }

    // ---- one-time row registers (wave-uniform) for both sides ----
    float rx1[RPW], ry1[RPW], rz1[RPW], rc1[RPW];
    float rx2[RPW], ry2[RPW], rz2[RPW], rc2[RPW];
#pragma unroll
    for (int r = 0; r < RPW; r++) {
        const float* p = x1 + 3 * (base + row0 + r);
        rx1[r] = p[0]; ry1[r] = p[1]; rz1[r] = p[2];
        rc1[r] = NEG100C * fmaf(rx1[r], rx1[r],
                                fmaf(ry1[r], ry1[r], rz1[r] * rz1[r]));
        p = x2 + 3 * (base + row0 + r);
        rx2[r] = p[0]; ry2[r] = p[1]; rz2[r] = p[2];
        rc2[r] = NEG100C * fmaf(rx2[r], rx2[r],
                                fmaf(ry2[r], ry2[r], rz2[r] * rz2[r]));
    }
    __syncthreads();

    // ---- 50 Sinkhorn iterations, 2 per-batch barriers each ----
    unsigned int phase = 0;
    for (int it = 0; it < ITERS; it++) {
        if (it > 0) {   // fold fresh v into cd2.w (iter 0: v=0 -> w=P already)
#pragma unroll
            for (int k = 0; k < 8; k++) {
                int j = tid + THREADS * k;
                cd2[j].w = fmaf(C_LOG2E, gload(&v[base + j]), P2[k]);
            }
            __syncthreads();
        }
        // u_i = log_mu - log(sum_j K_ij e^{v_j} + eps)
        half_pass(cd2, rx1, ry1, rz1, rc1, u, base + row0, lane, log_mu);
        batch_barrier(bar, (unsigned)TILES * (++phase));   // publish u

#pragma unroll
        for (int k = 0; k < 8; k++) {          // fold fresh u into cd1.w
            int j = tid + THREADS * k;
            cd1[j].w = fmaf(C_LOG2E, gload(&u[base + j]), P1[k]);
        }
        __syncthreads();
        // v_j = log_nu - log(sum_i K_ij e^{u_i} + eps)
        half_pass(cd1, rx2, ry2, rz2, rc2, v, base + row0, lane, log_mu);
        batch_barrier(bar, (unsigned)TILES * (++phase));   // publish v
    }

    // ---- fused EMD epilogue: emd[b] = sum_ij exp2(t) * cost,
    //      cost = 0.01*(u_i+v_j) - 0.01*ln2 * t  (algebraically exact) ----
    float* cv = reinterpret_cast<float*>(cd1);   // cd1 space reused (8 KB)
#pragma unroll
    for (int k = 0; k < 8; k++) {
        int j = tid + THREADS * k;
        float vj = gload(&v[base + j]);
        cd2[j].w = fmaf(C_LOG2E, vj, P2[k]);
        cv[j] = 0.01f * vj;
    }
    __syncthreads();

    float rcc[RPW], su[RPW];
#pragma unroll
    for (int r = 0; r < RPW; r++) {
        float ur = gload(&u[base + row0 + r]);
        rcc[r] = fmaf(C_LOG2E, ur, rc1[r]);
        su[r]  = 0.01f * ur;
    }

    float eacc = 0.0f;
    for (int jc = 0; jc < NPT; jc += 128) {
        float4 y0 = cd2[jc + lane];
        float4 y1 = cd2[jc + 64 + lane];
        float cv0 = cv[jc + lane];
        float cv1 = cv[jc + 64 + lane];
#pragma unroll
        for (int r = 0; r < RPW; r++) {
            float t0 = fmaf(rx1[r], y0.x, rcc[r]);
            t0 = fmaf(ry1[r], y0.y, t0);
            t0 = fmaf(rz1[r], y0.z, t0);
            t0 += y0.w;
            float c0 = fmaf(-LN2_01, t0, su[r] + cv0);
            eacc = fmaf(fast_exp2(t0), c0, eacc);
            float t1 = fmaf(rx1[r], y1.x, rcc[r]);
            t1 = fmaf(ry1[r], y1.y, t1);
            t1 = fmaf(rz1[r], y1.z, t1);
            t1 += y1.w;
            float c1 = fmaf(-LN2_01, t1, su[r] + cv1);
            eacc = fmaf(fast_exp2(t1), c1, eacc);
        }
    }
#pragma unroll
    for (int m = 32; m >= 1; m >>= 1) eacc += __shfl_xor(eacc, m, 64);

    __syncthreads();   // all waves done reading cv before reusing cd1 space
    float* wsum = reinterpret_cast<float*>(cd1);
    if (lane == 0) wsum[wave] = eacc;
    __syncthreads();
    if (tid == 0) atomicAdd(&out[b], wsum[0] + wsum[1] + wsum[2] + wsum[3]);
}

// ---------------------------------------------------------------------------
extern "C" void kernel_launch(void* const* d_in, const int* in_sizes, int n_in,
                              void* d_out, int out_size, void* d_ws, size_t ws_size,
                              hipStream_t stream) {
    (void)in_sizes; (void)n_in; (void)out_size; (void)ws_size;
    const float* x1 = (const float*)d_in[0];
    const float* x2 = (const float*)d_in[1];
    float* out = (float*)d_out;

    char* ws = (char*)d_ws;
    float* u = (float*)ws;                           // NPTS floats
    float* v = u + NPTS;                             // NPTS floats
    unsigned int* ctr = (unsigned int*)(v + NPTS);   // BATCH*32 uints

    init_kernel<<<1, 256, 0, stream>>>(out, ctr);
    sinkhorn_kernel<<<GRID_MAIN, THREADS, 0, stream>>>(x1, x2, u, v, ctr, out);
}

// Round 4
// 958.276 us; speedup vs baseline: 2.0459x; 1.8144x over previous
//
#include <hip/hip_runtime.h>
#include <cmath>

// Problem constants (fixed by reference): B=8, N=2048, eps=0.01, 50 iters.
#define BATCH 8
#define NPT   2048
#define NPAIR (NPT / 2)               // 1024 column pairs
#define NPTS  (BATCH * NPT)
#define TILES 64                      // blocks per batch (32 rows each)
#define GRID_MAIN (BATCH * TILES)     // 512 blocks = 2/CU (64KB LDS -> both resident)
#define THREADS 256
#define RPW   8                       // rows per wave
#define ITERS 50

// exp(v_j - 100*cost) = exp2( C_LOG2E*v_j + NEG100C*(n_i + n_j) + S200C*dot )
#define C_LOG2E 1.4426950408889634f
#define NEG100C (-144.26950408889634f)   // -100 * log2(e)
#define S200C   288.53900817779268f      //  200 * log2(e)
#define EPS_LOG 1e-8f
#define LN2_01  0.006931471805599453f    // 0.01 * ln(2)

typedef float v2f __attribute__((ext_vector_type(2)));
typedef float v4f __attribute__((ext_vector_type(4)));

static __device__ __forceinline__ float fast_exp2(float x) {
#if __has_builtin(__builtin_amdgcn_exp2f)
    return __builtin_amdgcn_exp2f(x);   // raw v_exp_f32
#else
    return exp2f(x);
#endif
}

// Coherence-point (agent-scope, relaxed) accessors for cross-block data.
static __device__ __forceinline__ float gload(const float* p) {
    return __hip_atomic_load(p, __ATOMIC_RELAXED, __HIP_MEMORY_SCOPE_AGENT);
}
static __device__ __forceinline__ void gstore(float* p, float val) {
    __hip_atomic_store(p, val, __ATOMIC_RELAXED, __HIP_MEMORY_SCOPE_AGENT);
}

// ---------------------------------------------------------------------------
// Tiny init: zero EMD outputs and per-batch flag arrays.
// ---------------------------------------------------------------------------
__global__ void init_kernel(float* __restrict__ out,
                            unsigned int* __restrict__ flags) {
    int t = threadIdx.x;          // 512 threads
    if (t < BATCH) out[t] = 0.0f;
    flags[t] = 0u;                // BATCH*TILES = 512 flags
}

// ---------------------------------------------------------------------------
// Flag-array barrier: NO atomic RMW, NO acquire ops.
//  - arrival: relaxed sc1 store of the phase number to this block's slot
//    (u-data stores are already drained by __syncthreads' vmcnt(0)).
//  - wait: wave 0, lane l spins (relaxed, exec-masked) on flags[l] >= phase.
// Detection latency ~ one poll round; zero same-line RMW contention.
// ---------------------------------------------------------------------------
static __device__ __forceinline__ void flag_barrier(unsigned int* bflags,
                                                    int tile, int wave,
                                                    int lane,
                                                    unsigned int phase) {
    __syncthreads();
    if (wave == 0) {
        if (lane == 0)
            __hip_atomic_store(&bflags[tile], phase, __ATOMIC_RELAXED,
                               __HIP_MEMORY_SCOPE_AGENT);
        while (__hip_atomic_load(&bflags[lane], __ATOMIC_RELAXED,
                                 __HIP_MEMORY_SCOPE_AGENT) < phase) {
            __builtin_amdgcn_s_sleep(1);
        }
    }
    __syncthreads();
    __builtin_amdgcn_sched_barrier(0);   // no code motion across the barrier
}

// ---------------------------------------------------------------------------
// One Sinkhorn half-step over pair-packed LDS column tiles:
//   dual_out_i = log_mu - log( sum_j exp2( dot_scl + rc_i + w_j ) + 1e-8 )
// cdXY[q] = (x0,x1,y0,y1) scaled; cdZW[q] = (z0,z1,w0,w1) (w = P + log2e*dual)
// Two columns per v_pk_fma_f32.
// ---------------------------------------------------------------------------
static __device__ __forceinline__ void half_pass(
        const v4f* cdXY, const v4f* cdZW,
        const v2f (&rx)[RPW], const v2f (&ry)[RPW],
        const v2f (&rz)[RPW], const v2f (&rc)[RPW],
        float* __restrict__ dual_out, int outbase, int lane, float log_mu)
{
    v2f acc[RPW];
#pragma unroll
    for (int r = 0; r < RPW; r++) acc[r] = (v2f){0.0f, 0.0f};

#pragma unroll 2
    for (int jp = 0; jp < NPAIR; jp += 64) {
        v4f a  = cdXY[jp + lane];                       // ds_read_b128
        v4f bz = cdZW[jp + lane];                       // ds_read_b128
        v2f xx = __builtin_shufflevector(a,  a,  0, 1);
        v2f yy = __builtin_shufflevector(a,  a,  2, 3);
        v2f zz = __builtin_shufflevector(bz, bz, 0, 1);
        v2f ww = __builtin_shufflevector(bz, bz, 2, 3);
#pragma unroll
        for (int r = 0; r < RPW; r++) {
            v2f t = xx * rx[r] + ww;      // v_pk_fma_f32
            t = yy * ry[r] + t;
            t = zz * rz[r] + t;
            t = t + rc[r];
            v2f e;
            e.x = fast_exp2(t.x);
            e.y = fast_exp2(t.y);
            acc[r] += e;
        }
    }

    // Reduce: per-row lane sums -> butterfly -> lane r holds row r's total.
    float sel = 1.0f;
#pragma unroll
    for (int r = 0; r < RPW; r++) {
        float s = acc[r].x + acc[r].y;
#pragma unroll
        for (int m = 32; m >= 1; m >>= 1) s += __shfl_xor(s, m, 64);
        if (lane == r) sel = s;
    }
    float res = log_mu - __logf(sel + EPS_LOG);
    if (lane < RPW) gstore(&dual_out[outbase + lane], res);
}

// ---------------------------------------------------------------------------
// Fused persistent kernel: stage both pair-packed column tiles once, run all
// 50 iterations with flag barriers, fused EMD epilogue.
// LDS = 4 * 16 KB = 64 KB; 512 blocks -> 2/CU, all resident.
// ---------------------------------------------------------------------------
__global__ __launch_bounds__(THREADS) void sinkhorn_kernel(
        const float* __restrict__ x1, const float* __restrict__ x2,
        float* __restrict__ u, float* __restrict__ v,
        unsigned int* __restrict__ flags, float* __restrict__ out)
{
    __shared__ v4f cd1XY[NPAIR], cd1ZW[NPAIR];   // side-1 (dual = u)
    __shared__ v4f cd2XY[NPAIR], cd2ZW[NPAIR];   // side-2 (dual = v)

    const int b    = blockIdx.x / TILES;
    const int tile = blockIdx.x % TILES;
    const int base = b * NPT;
    unsigned int* bflags = flags + b * TILES;

    const int tid  = threadIdx.x;
    const int wave = tid >> 6;
    const int lane = tid & 63;
    const int row0 = tile * 32 + wave * RPW;

    const float log_mu = logf(1.0f / (float)NPT + EPS_LOG);   // == log_nu

    // ---- one-time pair-packed column staging ----
    float P1a[4], P1b[4], P2a[4], P2b[4];
#pragma unroll
    for (int k = 0; k < 4; k++) {
        int q = tid + THREADS * k;              // pair index 0..1023
        const float* p = x1 + 3 * (base + 2 * q);
        float ax = p[0], ay = p[1], az = p[2];
        float bx = p[3], by = p[4], bz = p[5];
        float na = fmaf(ax, ax, fmaf(ay, ay, az * az));
        float nb = fmaf(bx, bx, fmaf(by, by, bz * bz));
        P1a[k] = na * NEG100C;  P1b[k] = nb * NEG100C;
        cd1XY[q] = (v4f){ax * S200C, bx * S200C, ay * S200C, by * S200C};
        cd1ZW[q] = (v4f){az * S200C, bz * S200C, P1a[k], P1b[k]};

        p = x2 + 3 * (base + 2 * q);
        ax = p[0]; ay = p[1]; az = p[2];
        bx = p[3]; by = p[4]; bz = p[5];
        na = fmaf(ax, ax, fmaf(ay, ay, az * az));
        nb = fmaf(bx, bx, fmaf(by, by, bz * bz));
        P2a[k] = na * NEG100C;  P2b[k] = nb * NEG100C;
        cd2XY[q] = (v4f){ax * S200C, bx * S200C, ay * S200C, by * S200C};
        cd2ZW[q] = (v4f){az * S200C, bz * S200C, P2a[k], P2b[k]};
    }

    // ---- one-time row registers (wave-uniform splats) for both sides ----
    v2f rx1[RPW], ry1[RPW], rz1[RPW], rc1[RPW];
    v2f rx2[RPW], ry2[RPW], rz2[RPW], rc2[RPW];
    float rc1s[RPW];
#pragma unroll
    for (int r = 0; r < RPW; r++) {
        const float* p = x1 + 3 * (base + row0 + r);
        float a = p[0], bb = p[1], c = p[2];
        float nn = NEG100C * fmaf(a, a, fmaf(bb, bb, c * c));
        rx1[r] = (v2f){a, a};  ry1[r] = (v2f){bb, bb};
        rz1[r] = (v2f){c, c};  rc1[r] = (v2f){nn, nn};
        rc1s[r] = nn;
        p = x2 + 3 * (base + row0 + r);
        a = p[0]; bb = p[1]; c = p[2];
        nn = NEG100C * fmaf(a, a, fmaf(bb, bb, c * c));
        rx2[r] = (v2f){a, a};  ry2[r] = (v2f){bb, bb};
        rz2[r] = (v2f){c, c};  rc2[r] = (v2f){nn, nn};
    }
    __syncthreads();

    // ---- 50 Sinkhorn iterations, 2 flag barriers each ----
    unsigned int phase = 0;
    for (int it = 0; it < ITERS; it++) {
        if (it > 0) {   // fold fresh v into cd2 w-slots (iter 0: w=P already)
#pragma unroll
            for (int k = 0; k < 4; k++) {
                int q = tid + THREADS * k;
                float va = gload(&v[base + 2 * q]);
                float vb = gload(&v[base + 2 * q + 1]);
                v2f wnew = {fmaf(C_LOG2E, va, P2a[k]),
                            fmaf(C_LOG2E, vb, P2b[k])};
                reinterpret_cast<v2f*>(&cd2ZW[q])[1] = wnew;  // ds_write_b64
            }
            __syncthreads();
        }
        // u_i = log_mu - log(sum_j K_ij e^{v_j} + eps)
        half_pass(cd2XY, cd2ZW, rx1, ry1, rz1, rc1, u, base + row0, lane, log_mu);
        flag_barrier(bflags, tile, wave, lane, ++phase);   // publish u

#pragma unroll
        for (int k = 0; k < 4; k++) {          // fold fresh u into cd1 w-slots
            int q = tid + THREADS * k;
            float ua = gload(&u[base + 2 * q]);
            float ub = gload(&u[base + 2 * q + 1]);
            v2f wnew = {fmaf(C_LOG2E, ua, P1a[k]),
                        fmaf(C_LOG2E, ub, P1b[k])};
            reinterpret_cast<v2f*>(&cd1ZW[q])[1] = wnew;
        }
        __syncthreads();
        // v_j = log_nu - log(sum_i K_ij e^{u_i} + eps)
        half_pass(cd1XY, cd1ZW, rx2, ry2, rz2, rc2, v, base + row0, lane, log_mu);
        flag_barrier(bflags, tile, wave, lane, ++phase);   // publish v
    }

    // ---- fused EMD epilogue: emd[b] = sum_ij exp2(t) * cost,
    //      cost = 0.01*(u_i+v_j) - 0.01*ln2 * t  (algebraically exact) ----
    v2f* cvp = reinterpret_cast<v2f*>(cd1XY);   // cd1XY space reused (8 KB)
#pragma unroll
    for (int k = 0; k < 4; k++) {
        int q = tid + THREADS * k;
        float va = gload(&v[base + 2 * q]);
        float vb = gload(&v[base + 2 * q + 1]);
        reinterpret_cast<v2f*>(&cd2ZW[q])[1] =
            (v2f){fmaf(C_LOG2E, va, P2a[k]), fmaf(C_LOG2E, vb, P2b[k])};
        cvp[q] = (v2f){0.01f * va, 0.01f * vb};
    }
    __syncthreads();

    v2f rcc[RPW], su[RPW];
#pragma unroll
    for (int r = 0; r < RPW; r++) {
        float ur  = gload(&u[base + row0 + r]);
        float rcs = fmaf(C_LOG2E, ur, rc1s[r]);
        rcc[r] = (v2f){rcs, rcs};
        float sus = 0.01f * ur;
        su[r] = (v2f){sus, sus};
    }

    const v2f NL2 = {-LN2_01, -LN2_01};
    v2f eacc = {0.0f, 0.0f};
#pragma unroll 2
    for (int jp = 0; jp < NPAIR; jp += 64) {
        v4f a   = cd2XY[jp + lane];
        v4f bz  = cd2ZW[jp + lane];
        v2f cv2 = cvp[jp + lane];
        v2f xx = __builtin_shufflevector(a,  a,  0, 1);
        v2f yy = __builtin_shufflevector(a,  a,  2, 3);
        v2f zz = __builtin_shufflevector(bz, bz, 0, 1);
        v2f ww = __builtin_shufflevector(bz, bz, 2, 3);
#pragma unroll
        for (int r = 0; r < RPW; r++) {
            v2f t = xx * rx1[r] + ww;
            t = yy * ry1[r] + t;
            t = zz * rz1[r] + t;
            t = t + rcc[r];
            v2f c2 = su[r] + cv2;
            c2 = t * NL2 + c2;
            v2f e;
            e.x = fast_exp2(t.x);
            e.y = fast_exp2(t.y);
            eacc = e * c2 + eacc;
        }
    }
    float es = eacc.x + eacc.y;
#pragma unroll
    for (int m = 32; m >= 1; m >>= 1) es += __shfl_xor(es, m, 64);

    float* wsum = reinterpret_cast<float*>(cd2XY);   // free space, no reader
    if (lane == 0) wsum[wave] = es;
    __syncthreads();
    if (tid == 0) atomicAdd(&out[b], wsum[0] + wsum[1] + wsum[2] + wsum[3]);
}

// ---------------------------------------------------------------------------
extern "C" void kernel_launch(void* const* d_in, const int* in_sizes, int n_in,
                              void* d_out, int out_size, void* d_ws, size_t ws_size,
                              hipStream_t stream) {
    (void)in_sizes; (void)n_in; (void)out_size; (void)ws_size;
    const float* x1 = (const float*)d_in[0];
    const float* x2 = (const float*)d_in[1];
    float* out = (float*)d_out;

    char* ws = (char*)d_ws;
    float* u = (float*)ws;                             // NPTS floats
    float* v = u + NPTS;                               // NPTS floats
    unsigned int* flags = (unsigned int*)(v + NPTS);   // BATCH*TILES uints

    init_kernel<<<1, 512, 0, stream>>>(out, flags);
    sinkhorn_kernel<<<GRID_MAIN, THREADS, 0, stream>>>(x1, x2, u, v, flags, out);
}

// Round 5
// 841.675 us; speedup vs baseline: 2.3293x; 1.1385x over previous
//
#include <hip/hip_runtime.h>
#include <cmath>

// Problem constants (fixed by reference): B=8, N=2048, eps=0.01, 50 iters.
#define BATCH 8
#define NPT   2048
#define NPAIR (NPT / 2)               // 1024 column pairs
#define NPTS  (BATCH * NPT)
#define TILES 64                      // blocks per batch (32 rows each)
#define GRID_MAIN (BATCH * TILES)     // 512 blocks = 2/CU (64KB LDS -> both resident)
#define THREADS 512                   // 8 waves/block -> 16 waves/CU = 4/SIMD
#define RPW   4                       // rows per wave
#define ITERS 50

// exp(v_j - 100*cost) = exp2( C_LOG2E*v_j + NEG100C*(n_i + n_j) + S200C*dot )
#define C_LOG2E 1.4426950408889634f
#define NEG100C (-144.26950408889634f)   // -100 * log2(e)
#define S200C   288.53900817779268f      //  200 * log2(e)
#define EPS_LOG 1e-8f
#define LN2_01  0.006931471805599453f    // 0.01 * ln(2)

typedef float v2f __attribute__((ext_vector_type(2)));
typedef float v4f __attribute__((ext_vector_type(4)));

static __device__ __forceinline__ float fast_exp2(float x) {
#if __has_builtin(__builtin_amdgcn_exp2f)
    return __builtin_amdgcn_exp2f(x);   // raw v_exp_f32
#else
    return exp2f(x);
#endif
}

// Coherence-point (agent-scope, relaxed) accessors for cross-block data.
static __device__ __forceinline__ float gload(const float* p) {
    return __hip_atomic_load(p, __ATOMIC_RELAXED, __HIP_MEMORY_SCOPE_AGENT);
}
static __device__ __forceinline__ void gstore(float* p, float val) {
    __hip_atomic_store(p, val, __ATOMIC_RELAXED, __HIP_MEMORY_SCOPE_AGENT);
}

// ---------------------------------------------------------------------------
// Tiny init: zero EMD outputs and per-batch flag arrays.
// ---------------------------------------------------------------------------
__global__ void init_kernel(float* __restrict__ out,
                            unsigned int* __restrict__ flags) {
    int t = threadIdx.x;          // 512 threads
    if (t < BATCH) out[t] = 0.0f;
    flags[t] = 0u;                // BATCH*TILES = 512 flags
}

// ---------------------------------------------------------------------------
// Flag-array barrier: NO atomic RMW, NO acquire ops.
//  - arrival: relaxed sc1 store of the phase number to this block's slot
//    (data stores already drained by __syncthreads' vmcnt(0)).
//  - wait: wave 0, lane l spins (relaxed, exec-masked) on flags[l] >= phase.
// ---------------------------------------------------------------------------
static __device__ __forceinline__ void flag_barrier(unsigned int* bflags,
                                                    int tile, int wave,
                                                    int lane,
                                                    unsigned int phase) {
    __syncthreads();
    if (wave == 0) {
        if (lane == 0)
            __hip_atomic_store(&bflags[tile], phase, __ATOMIC_RELAXED,
                               __HIP_MEMORY_SCOPE_AGENT);
        while (__hip_atomic_load(&bflags[lane], __ATOMIC_RELAXED,
                                 __HIP_MEMORY_SCOPE_AGENT) < phase) {
            __builtin_amdgcn_s_sleep(1);
        }
    }
    __syncthreads();
    __builtin_amdgcn_sched_barrier(0);   // no code motion across the barrier
}

// ---------------------------------------------------------------------------
// One Sinkhorn half-step over pair-packed LDS column tiles:
//   dual_out_i = log_mu - log( sum_j exp2( dot_scl + rc_i + w_j ) + 1e-8 )
// cdXY[q] = (x0,x1,y0,y1) scaled; cdZW[q] = (z0,z1,w0,w1) (w = P + log2e*dual)
// Two columns per v_pk_fma_f32.
// ---------------------------------------------------------------------------
static __device__ __forceinline__ void half_pass(
        const v4f* cdXY, const v4f* cdZW,
        const v2f (&rx)[RPW], const v2f (&ry)[RPW],
        const v2f (&rz)[RPW], const v2f (&rc)[RPW],
        float* __restrict__ dual_out, int outbase, int lane, float log_mu)
{
    v2f acc[RPW];
#pragma unroll
    for (int r = 0; r < RPW; r++) acc[r] = (v2f){0.0f, 0.0f};

#pragma unroll 2
    for (int jp = 0; jp < NPAIR; jp += 64) {
        v4f a  = cdXY[jp + lane];                       // ds_read_b128
        v4f bz = cdZW[jp + lane];                       // ds_read_b128
        v2f xx = __builtin_shufflevector(a,  a,  0, 1);
        v2f yy = __builtin_shufflevector(a,  a,  2, 3);
        v2f zz = __builtin_shufflevector(bz, bz, 0, 1);
        v2f ww = __builtin_shufflevector(bz, bz, 2, 3);
#pragma unroll
        for (int r = 0; r < RPW; r++) {
            v2f t = xx * rx[r] + ww;      // v_pk_fma_f32
            t = yy * ry[r] + t;
            t = zz * rz[r] + t;
            t = t + rc[r];
            v2f e;
            e.x = fast_exp2(t.x);
            e.y = fast_exp2(t.y);
            acc[r] += e;
        }
    }

    // Reduce: per-row lane sums -> butterfly -> lane r holds row r's total.
    float sel = 1.0f;
#pragma unroll
    for (int r = 0; r < RPW; r++) {
        float s = acc[r].x + acc[r].y;
#pragma unroll
        for (int m = 32; m >= 1; m >>= 1) s += __shfl_xor(s, m, 64);
        if (lane == r) sel = s;
    }
    float res = log_mu - __logf(sel + EPS_LOG);
    if (lane < RPW) gstore(&dual_out[outbase + lane], res);
}

// ---------------------------------------------------------------------------
// Fused persistent kernel: stage both pair-packed column tiles once, run all
// 50 iterations with flag barriers, fused EMD epilogue.
// LDS = 64 KB; 512 blocks x 512 threads -> 2 blocks/CU, 16 waves/CU (4/SIMD).
// ---------------------------------------------------------------------------
__global__ __launch_bounds__(THREADS, 4) void sinkhorn_kernel(
        const float* __restrict__ x1, const float* __restrict__ x2,
        float* __restrict__ u, float* __restrict__ v,
        unsigned int* __restrict__ flags, float* __restrict__ out)
{
    __shared__ v4f cd1XY[NPAIR], cd1ZW[NPAIR];   // side-1 (dual = u)
    __shared__ v4f cd2XY[NPAIR], cd2ZW[NPAIR];   // side-2 (dual = v)

    const int b    = blockIdx.x / TILES;
    const int tile = blockIdx.x % TILES;
    const int base = b * NPT;
    unsigned int* bflags = flags + b * TILES;

    const int tid  = threadIdx.x;
    const int wave = tid >> 6;
    const int lane = tid & 63;
    const int row0 = tile * 32 + wave * RPW;

    const float log_mu = logf(1.0f / (float)NPT + EPS_LOG);   // == log_nu

    // ---- one-time pair-packed column staging (2 k-slots @ 512 threads) ----
    float P1a[2], P1b[2], P2a[2], P2b[2];
#pragma unroll
    for (int k = 0; k < 2; k++) {
        int q = tid + THREADS * k;              // pair index 0..1023
        const float* p = x1 + 3 * (base + 2 * q);
        float ax = p[0], ay = p[1], az = p[2];
        float bx = p[3], by = p[4], bz = p[5];
        float na = fmaf(ax, ax, fmaf(ay, ay, az * az));
        float nb = fmaf(bx, bx, fmaf(by, by, bz * bz));
        P1a[k] = na * NEG100C;  P1b[k] = nb * NEG100C;
        cd1XY[q] = (v4f){ax * S200C, bx * S200C, ay * S200C, by * S200C};
        cd1ZW[q] = (v4f){az * S200C, bz * S200C, P1a[k], P1b[k]};

        p = x2 + 3 * (base + 2 * q);
        ax = p[0]; ay = p[1]; az = p[2];
        bx = p[3]; by = p[4]; bz = p[5];
        na = fmaf(ax, ax, fmaf(ay, ay, az * az));
        nb = fmaf(bx, bx, fmaf(by, by, bz * bz));
        P2a[k] = na * NEG100C;  P2b[k] = nb * NEG100C;
        cd2XY[q] = (v4f){ax * S200C, bx * S200C, ay * S200C, by * S200C};
        cd2ZW[q] = (v4f){az * S200C, bz * S200C, P2a[k], P2b[k]};
    }

    // ---- one-time row registers (wave-uniform splats) for both sides ----
    v2f rx1[RPW], ry1[RPW], rz1[RPW], rc1[RPW];
    v2f rx2[RPW], ry2[RPW], rz2[RPW], rc2[RPW];
    float rc1s[RPW];
#pragma unroll
    for (int r = 0; r < RPW; r++) {
        const float* p = x1 + 3 * (base + row0 + r);
        float a = p[0], bb = p[1], c = p[2];
        float nn = NEG100C * fmaf(a, a, fmaf(bb, bb, c * c));
        rx1[r] = (v2f){a, a};  ry1[r] = (v2f){bb, bb};
        rz1[r] = (v2f){c, c};  rc1[r] = (v2f){nn, nn};
        rc1s[r] = nn;
        p = x2 + 3 * (base + row0 + r);
        a = p[0]; bb = p[1]; c = p[2];
        nn = NEG100C * fmaf(a, a, fmaf(bb, bb, c * c));
        rx2[r] = (v2f){a, a};  ry2[r] = (v2f){bb, bb};
        rz2[r] = (v2f){c, c};  rc2[r] = (v2f){nn, nn};
    }
    __syncthreads();

    // ---- 50 Sinkhorn iterations, 2 flag barriers each ----
    unsigned int phase = 0;
    for (int it = 0; it < ITERS; it++) {
        if (it > 0) {   // fold fresh v into cd2 w-slots (iter 0: w=P already)
#pragma unroll
            for (int k = 0; k < 2; k++) {
                int q = tid + THREADS * k;
                float va = gload(&v[base + 2 * q]);
                float vb = gload(&v[base + 2 * q + 1]);
                v2f wnew = {fmaf(C_LOG2E, va, P2a[k]),
                            fmaf(C_LOG2E, vb, P2b[k])};
                reinterpret_cast<v2f*>(&cd2ZW[q])[1] = wnew;  // ds_write_b64
            }
            __syncthreads();
        }
        // u_i = log_mu - log(sum_j K_ij e^{v_j} + eps)
        half_pass(cd2XY, cd2ZW, rx1, ry1, rz1, rc1, u, base + row0, lane, log_mu);
        flag_barrier(bflags, tile, wave, lane, ++phase);   // publish u

#pragma unroll
        for (int k = 0; k < 2; k++) {          // fold fresh u into cd1 w-slots
            int q = tid + THREADS * k;
            float ua = gload(&u[base + 2 * q]);
            float ub = gload(&u[base + 2 * q + 1]);
            v2f wnew = {fmaf(C_LOG2E, ua, P1a[k]),
                        fmaf(C_LOG2E, ub, P1b[k])};
            reinterpret_cast<v2f*>(&cd1ZW[q])[1] = wnew;
        }
        __syncthreads();
        // v_j = log_nu - log(sum_i K_ij e^{u_i} + eps)
        half_pass(cd1XY, cd1ZW, rx2, ry2, rz2, rc2, v, base + row0, lane, log_mu);
        flag_barrier(bflags, tile, wave, lane, ++phase);   // publish v
    }

    // ---- fused EMD epilogue: emd[b] = sum_ij exp2(t) * cost,
    //      cost = 0.01*(u_i+v_j) - 0.01*ln2 * t  (algebraically exact) ----
    v2f* cvp = reinterpret_cast<v2f*>(cd1XY);   // cd1XY space reused (8 KB)
#pragma unroll
    for (int k = 0; k < 2; k++) {
        int q = tid + THREADS * k;
        float va = gload(&v[base + 2 * q]);
        float vb = gload(&v[base + 2 * q + 1]);
        reinterpret_cast<v2f*>(&cd2ZW[q])[1] =
            (v2f){fmaf(C_LOG2E, va, P2a[k]), fmaf(C_LOG2E, vb, P2b[k])};
        cvp[q] = (v2f){0.01f * va, 0.01f * vb};
    }
    __syncthreads();

    v2f rcc[RPW], su[RPW];
#pragma unroll
    for (int r = 0; r < RPW; r++) {
        float ur  = gload(&u[base + row0 + r]);
        float rcs = fmaf(C_LOG2E, ur, rc1s[r]);
        rcc[r] = (v2f){rcs, rcs};
        float sus = 0.01f * ur;
        su[r] = (v2f){sus, sus};
    }

    const v2f NL2 = {-LN2_01, -LN2_01};
    v2f eacc = {0.0f, 0.0f};
#pragma unroll 2
    for (int jp = 0; jp < NPAIR; jp += 64) {
        v4f a   = cd2XY[jp + lane];
        v4f bz  = cd2ZW[jp + lane];
        v2f cv2 = cvp[jp + lane];
        v2f xx = __builtin_shufflevector(a,  a,  0, 1);
        v2f yy = __builtin_shufflevector(a,  a,  2, 3);
        v2f zz = __builtin_shufflevector(bz, bz, 0, 1);
        v2f ww = __builtin_shufflevector(bz, bz, 2, 3);
#pragma unroll
        for (int r = 0; r < RPW; r++) {
            v2f t = xx * rx1[r] + ww;
            t = yy * ry1[r] + t;
            t = zz * rz1[r] + t;
            t = t + rcc[r];
            v2f c2 = su[r] + cv2;
            c2 = t * NL2 + c2;
            v2f e;
            e.x = fast_exp2(t.x);
            e.y = fast_exp2(t.y);
            eacc = e * c2 + eacc;
        }
    }
    float es = eacc.x + eacc.y;
#pragma unroll
    for (int m = 32; m >= 1; m >>= 1) es += __shfl_xor(es, m, 64);

    float* wsum = reinterpret_cast<float*>(cd2XY);   // free space, no reader
    if (lane == 0) wsum[wave] = es;
    __syncthreads();
    if (tid == 0) {
        float s = 0.0f;
#pragma unroll
        for (int w = 0; w < THREADS / 64; w++) s += wsum[w];
        atomicAdd(&out[b], s);
    }
}

// ---------------------------------------------------------------------------
extern "C" void kernel_launch(void* const* d_in, const int* in_sizes, int n_in,
                              void* d_out, int out_size, void* d_ws, size_t ws_size,
                              hipStream_t stream) {
    (void)in_sizes; (void)n_in; (void)out_size; (void)ws_size;
    const float* x1 = (const float*)d_in[0];
    const float* x2 = (const float*)d_in[1];
    float* out = (float*)d_out;

    char* ws = (char*)d_ws;
    float* u = (float*)ws;                             // NPTS floats
    float* v = u + NPTS;                               // NPTS floats
    unsigned int* flags = (unsigned int*)(v + NPTS);   // BATCH*TILES uints

    init_kernel<<<1, 512, 0, stream>>>(out, flags);
    sinkhorn_kernel<<<GRID_MAIN, THREADS, 0, stream>>>(x1, x2, u, v, flags, out);
}